// Round 1
// 8794.704 us; speedup vs baseline: 2.4699x; 2.4699x over previous
//
#include <hip/hip_runtime.h>
#include <stdint.h>

#define NN 8192
#define D 256
#define DA 64
#define CAND 2048

typedef unsigned short ushort_t;

// ---- f32 block reductions (256-thread blocks, 4 waves) ----
__device__ float blockSumF(float v, float* scr) {
  __syncthreads();
#pragma unroll
  for (int o = 32; o > 0; o >>= 1) v += __shfl_down(v, o, 64);
  if ((threadIdx.x & 63) == 0) scr[threadIdx.x >> 6] = v;
  __syncthreads();
  return ((scr[0] + scr[1]) + (scr[2] + scr[3]));
}
__device__ float blockMaxF(float v, float* scr) {
  __syncthreads();
#pragma unroll
  for (int o = 32; o > 0; o >>= 1) v = fmaxf(v, __shfl_down(v, o, 64));
  if ((threadIdx.x & 63) == 0) scr[threadIdx.x >> 6] = v;
  __syncthreads();
  return fmaxf(fmaxf(scr[0], scr[1]), fmaxf(scr[2], scr[3]));
}

// ---- zero a float buffer ----
__global__ void zero_kernel(float* __restrict__ p, size_t n) {
  for (size_t i = (size_t)blockIdx.x * blockDim.x + threadIdx.x; i < n;
       i += (size_t)gridDim.x * blockDim.x)
    p[i] = 0.0f;
}

// ---- den[i] = 1 + sum_j S[i][j] ----
__global__ __launch_bounds__(256) void rowsum_kernel(const float* __restrict__ S, float* __restrict__ den) {
  __shared__ float scr[4];
  int row = blockIdx.x, tid = threadIdx.x;
  const float* sr = S + (size_t)row * NN;
  float s = 0;
  for (int c = tid * 4; c < NN; c += 1024) {
    float4 u = *(const float4*)(sr + c);
    s += (u.x + u.y) + (u.z + u.w);
  }
  float tot = blockSumF(s, scr);
  if (tid == 0) den[row] = tot + 1.0f;
}

// ---- Xf_next = (S@Xf + Xf)/den : tiled f32 GEMM, fused epilogue ----
__global__ __launch_bounds__(256) void xf_gemm(const float* __restrict__ S,
                                               const float* __restrict__ XfC,
                                               const float* __restrict__ den,
                                               float* __restrict__ XfN) {
  __shared__ float As[64][65];
  __shared__ float Bs[64][65];
  int tid = threadIdx.x;
  int tx = tid & 15, ty = tid >> 4;
  int rb = blockIdx.x * 64;
  int cb = blockIdx.y * 64;
  float acc[4][4] = {};
  for (int kt = 0; kt < NN; kt += 64) {
    for (int i = tid; i < 4096; i += 256) {
      int r = i >> 6, c = i & 63;
      As[r][c] = S[(size_t)(rb + r) * NN + kt + c];
      Bs[r][c] = XfC[(size_t)(kt + r) * D + cb + c];
    }
    __syncthreads();
#pragma unroll 8
    for (int k = 0; k < 64; k++) {
      float a0 = As[ty * 4][k], a1 = As[ty * 4 + 1][k];
      float a2 = As[ty * 4 + 2][k], a3 = As[ty * 4 + 3][k];
      float b0 = Bs[k][tx * 4], b1 = Bs[k][tx * 4 + 1];
      float b2 = Bs[k][tx * 4 + 2], b3 = Bs[k][tx * 4 + 3];
      acc[0][0] += a0 * b0; acc[0][1] += a0 * b1; acc[0][2] += a0 * b2; acc[0][3] += a0 * b3;
      acc[1][0] += a1 * b0; acc[1][1] += a1 * b1; acc[1][2] += a1 * b2; acc[1][3] += a1 * b3;
      acc[2][0] += a2 * b0; acc[2][1] += a2 * b1; acc[2][2] += a2 * b2; acc[2][3] += a2 * b3;
      acc[3][0] += a3 * b0; acc[3][1] += a3 * b1; acc[3][2] += a3 * b2; acc[3][3] += a3 * b3;
    }
    __syncthreads();
  }
#pragma unroll
  for (int i = 0; i < 4; i++) {
    int r = rb + ty * 4 + i;
    float dinv = 1.0f / den[r];
#pragma unroll
    for (int j = 0; j < 4; j++) {
      int c = cb + tx * 4 + j;
      XfN[(size_t)r * D + c] = (acc[i][j] + XfC[(size_t)r * D + c]) * dinv;
    }
  }
}

// ---- q,k f32: T1 = Xa@W1^T (materialized), q = T1@W2^T, k = Xa@W3^T ----
__global__ __launch_bounds__(64) void qk32_kernel(const float* __restrict__ Xa,
    const float* __restrict__ W1, const float* __restrict__ W2, const float* __restrict__ W3,
    float* __restrict__ qf, float* __restrict__ kf) {
  __shared__ float x[D];
  __shared__ float ts[DA];
  int row = blockIdx.x, tid = threadIdx.x;
  for (int i = tid; i < D; i += 64) x[i] = Xa[(size_t)row * D + i];
  __syncthreads();
  const float* w1r = W1 + (size_t)tid * D;
  const float* w3r = W3 + (size_t)tid * D;
  float t = 0.0f, kv = 0.0f;
  for (int d = 0; d < D; d++) {
    float xv = x[d];
    t  = fmaf(xv, w1r[d], t);
    kv = fmaf(xv, w3r[d], kv);
  }
  kf[(size_t)row * DA + tid] = kv;
  ts[tid] = t;
  __syncthreads();
  const float* w2r = W2 + (size_t)tid * DA;
  float qv = 0.0f;
  for (int a = 0; a < DA; a++) qv = fmaf(ts[a], w2r[a], qv);
  qf[(size_t)row * DA + tid] = qv;
}

// ---- L[chunk] = q @ k^T  f32 ----
__global__ __launch_bounds__(256) void logits32(const float* __restrict__ qf,
    const float* __restrict__ kf, float* __restrict__ L, int rowBase) {
  __shared__ float qs[64][65];
  __shared__ float ks[64][65];
  int tid = threadIdx.x;
  int tx = tid & 15, ty = tid >> 4;
  int colTile = blockIdx.x * 64;
  int rowTile = blockIdx.y * 64;
  for (int i = tid; i < 4096; i += 256) {
    int r = i >> 6, c = i & 63;
    qs[c][r] = qf[(size_t)(rowBase + rowTile + r) * DA + c];
    ks[c][r] = kf[(size_t)(colTile + r) * DA + c];
  }
  __syncthreads();
  float acc[4][4] = {};
  for (int c = 0; c < 64; c++) {
    float a0 = qs[c][ty * 4], a1 = qs[c][ty * 4 + 1];
    float a2 = qs[c][ty * 4 + 2], a3 = qs[c][ty * 4 + 3];
    float b0 = ks[c][tx * 4], b1 = ks[c][tx * 4 + 1];
    float b2 = ks[c][tx * 4 + 2], b3 = ks[c][tx * 4 + 3];
    acc[0][0] = fmaf(a0, b0, acc[0][0]); acc[0][1] = fmaf(a0, b1, acc[0][1]);
    acc[0][2] = fmaf(a0, b2, acc[0][2]); acc[0][3] = fmaf(a0, b3, acc[0][3]);
    acc[1][0] = fmaf(a1, b0, acc[1][0]); acc[1][1] = fmaf(a1, b1, acc[1][1]);
    acc[1][2] = fmaf(a1, b2, acc[1][2]); acc[1][3] = fmaf(a1, b3, acc[1][3]);
    acc[2][0] = fmaf(a2, b0, acc[2][0]); acc[2][1] = fmaf(a2, b1, acc[2][1]);
    acc[2][2] = fmaf(a2, b2, acc[2][2]); acc[2][3] = fmaf(a2, b3, acc[2][3]);
    acc[3][0] = fmaf(a3, b0, acc[3][0]); acc[3][1] = fmaf(a3, b1, acc[3][1]);
    acc[3][2] = fmaf(a3, b2, acc[3][2]); acc[3][3] = fmaf(a3, b3, acc[3][3]);
  }
#pragma unroll
  for (int i = 0; i < 4; i++)
#pragma unroll
    for (int j = 0; j < 4; j++)
      L[(size_t)(rowTile + ty * 4 + i) * NN + colTile + tx * 4 + j] = acc[i][j];
}

// ---- FULL-ROW top-p by SELECTION (no full sort). One block per row. ----
// softmax (np pairwise Z, identical to the full-sort version) ->
// bucket-histogram threshold t with mass(p>=t) >= 0.905 (margin over 0.9 covers
// f32 summation slop + dropped p<2^-30 tail of <=8e-6) ->
// compact candidates {p>=t} (upward-closed under the sort comparator, so their
// sorted order IS the prefix of the full sort) -> small bitonic sort ->
// identical sequential f32 cumsum with (cs - p) < 0.9f -> identical gather.
// Kept-set arithmetic is bitwise identical to the full-sort kernel.
__global__ __launch_bounds__(256) void topp_select(const float* __restrict__ L,
    const float* __restrict__ XaOld, float* __restrict__ XaNew, int rowBase) {
  __shared__ float ps[NN];        // 32 KB: logits, then probs (in place)
  __shared__ float cv[CAND];      // 8 KB: candidate probs
  __shared__ ushort_t ci[CAND];   // 4 KB: candidate indices
  __shared__ float hsum[256];     // 1 KB: per-bucket prob mass
  __shared__ int   hcnt[256];     // 1 KB: per-bucket count
  __shared__ float scr[4];
  __shared__ float zsh, asum_sh, thr_sh;
  __shared__ int kcs, ncand_sh, bsel_sh;
  int tid = threadIdx.x;
  const float* Lr = L + (size_t)blockIdx.x * NN;
  // 1. load logits (vectorized), row max
  float lm = -INFINITY;
  for (int c = tid * 4; c < NN; c += 1024) {
    float4 u = *(const float4*)(Lr + c);
    ps[c] = u.x; ps[c + 1] = u.y; ps[c + 2] = u.z; ps[c + 3] = u.w;
    lm = fmaxf(fmaxf(lm, fmaxf(u.x, u.y)), fmaxf(u.z, u.w));
  }
  float m = blockMaxF(lm, scr);   // entry barrier publishes ps
  // 2. Z = numpy pairwise_sum of exp(l - m): 64 leaves x 128 elems (8-acc base)
  if (tid < 64) {
    int base = tid * 128;
    float r[8];
#pragma unroll
    for (int j = 0; j < 8; j++) r[j] = expf(ps[base + j] - m);
    for (int i = 8; i < 128; i += 8)
#pragma unroll
      for (int j = 0; j < 8; j++) r[j] += expf(ps[base + i + j] - m);
    float leaf = ((r[0] + r[1]) + (r[2] + r[3])) + ((r[4] + r[5]) + (r[6] + r[7]));
#pragma unroll
    for (int off = 1; off < 64; off <<= 1) leaf += __shfl_down(leaf, off, 64);
    if (tid == 0) zsh = leaf;
  }
  // 3. init histogram
  hsum[tid] = 0.0f; hcnt[tid] = 0;
  __syncthreads();
  float z = zsh;
  // 4. probs in place + histogram. Bucket = (float_bits >> 20) - 768, i.e.
  // exponent + top-3 mantissa bits; monotone in p. b<=0 means p < ~2^-30:
  // skipped (total skipped mass <= 8192*2^-30 < 8e-6, covered by margin).
  for (int j = tid; j < NN; j += 256) {
    float p = expf(ps[j] - m) / z;
    ps[j] = p;
    int b = (int)(__float_as_uint(p) >> 20) - 768;
    if (b > 0) {
      if (b > 255) b = 255;
      atomicAdd(&hsum[b], p);
      atomicAdd(&hcnt[b], 1);
    }
  }
  __syncthreads();
  // 5. descending bucket scan: first bucket where cumulative mass >= 0.905
  if (tid == 0) {
    float cs = 0.0f; int cc = 0; int sel = 1;
    for (int b = 255; b >= 1; b--) {
      cs += hsum[b]; cc += hcnt[b];
      if (cs >= 0.905f) { sel = b; break; }
    }
    bsel_sh = sel;
    thr_sh = __uint_as_float((unsigned)((sel + 768) << 20));  // lower edge of bucket
    ncand_sh = cc;
  }
  __syncthreads();
  float thr = thr_sh;
  int ncand = ncand_sh;
  // 5b. rare path: boundary bucket too fat -> bisect a value threshold inside it
  if (ncand > CAND) {
    float lo = thr;                                            // S(lo) >= 0.905
    float hi = __uint_as_float((unsigned)((bsel_sh + 769) << 20));  // S(hi) < 0.905
    int cnt_lo = ncand;
    for (int it = 0; it < 24; it++) {
      float mid = 0.5f * (lo + hi);
      float s = 0.0f, c = 0.0f;
      for (int j = tid; j < NN; j += 256) {
        float p = ps[j];
        if (p >= mid) { s += p; c += 1.0f; }
      }
      s = blockSumF(s, scr);        // uniform across threads
      c = blockSumF(c, scr);
      if (s >= 0.905f) { lo = mid; cnt_lo = (int)(c + 0.5f); }
      else hi = mid;
      if (cnt_lo <= CAND) break;    // uniform break
    }
    thr = lo; ncand = cnt_lo;       // may still exceed CAND only with massive
                                    // duplicate probs in a ~1e-7 band (≈never)
  }
  // 6. compact candidates (unordered; sorted next)
  if (tid == 0) ncand_sh = 0;
  __syncthreads();
  for (int j = tid; j < NN; j += 256) {
    float p = ps[j];
    if (p >= thr) {
      int slot = atomicAdd(&ncand_sh, 1);
      if (slot < CAND) { cv[slot] = p; ci[slot] = (ushort_t)j; }
    }
  }
  __syncthreads();
  int nc = min(ncand_sh, CAND);
  // 7. pad to pow2 and bitonic sort: descending prob, ascending index tie-break
  int M = 2; while (M < nc) M <<= 1;
  for (int i = nc + tid; i < M; i += 256) { cv[i] = -1.0f; ci[i] = 0xFFFF; }
  __syncthreads();
  for (int size = 2; size <= M; size <<= 1) {
    for (int stride = size >> 1; stride > 0; stride >>= 1) {
      for (int i = tid; i < M; i += 256) {
        int j2 = i ^ stride;
        if (j2 > i) {
          float va = cv[i], vb = cv[j2];
          ushort_t ia = ci[i], ib = ci[j2];
          bool agtb = (va > vb) || (va == vb && ia < ib);
          bool desc = ((i & size) == 0);
          if (desc ? !agtb : agtb) { cv[i] = vb; cv[j2] = va; ci[i] = ib; ci[j2] = ia; }
        }
      }
      __syncthreads();
    }
  }
  // 8. literal np: sequential f32 inclusive cumsum; keep while f32(cs - p) < 0.9f
  if (tid == 0) {
    float cs = 0.0f, as = 0.0f; int kc = 0;
    while (kc < nc) {
      float p = cv[kc];
      cs += p;
      if (cs - p < 0.9f) { as += p; kc++; } else break;
    }
    kcs = kc; asum_sh = as;
  }
  __syncthreads();
  int kc = kcs;
  float asum = fmaxf(asum_sh, 1e-12f);   // jnp.maximum(A.sum, 1e-12)
  float acc = 0.0f;
  for (int i = 0; i < kc; i++)
    acc = fmaf(cv[i] / asum, XaOld[(size_t)ci[i] * D + tid], acc);
  XaNew[(size_t)(rowBase + blockIdx.x) * D + tid] = acc;
}

// ---- Z += Xf@U1^T + Xa@U2^T  (4 rows per block) ----
__global__ __launch_bounds__(256) void z_accum(const float* __restrict__ Xf, const float* __restrict__ Xa,
    const float* __restrict__ U1n, const float* __restrict__ U2n, float* __restrict__ Z) {
  __shared__ float xf[4][D];
  __shared__ float xa[4][D];
  int r0 = blockIdx.x * 4, tid = threadIdx.x;
  for (int i = tid; i < 4 * D; i += 256) {
    xf[i >> 8][i & 255] = Xf[(size_t)r0 * D + i];
    xa[i >> 8][i & 255] = Xa[(size_t)r0 * D + i];
  }
  __syncthreads();
  const float* u1r = U1n + (size_t)tid * D;
  const float* u2r = U2n + (size_t)tid * D;
  float a0 = 0, a1 = 0, a2 = 0, a3 = 0, b0 = 0, b1 = 0, b2 = 0, b3 = 0;
  for (int d = 0; d < D; d += 4) {
    float4 u1 = *(const float4*)(u1r + d);
    float4 u2 = *(const float4*)(u2r + d);
    float f1[4] = {u1.x, u1.y, u1.z, u1.w};
    float f2[4] = {u2.x, u2.y, u2.z, u2.w};
#pragma unroll
    for (int j = 0; j < 4; j++) {
      int dd = d + j;
      a0 += xf[0][dd] * f1[j]; a1 += xf[1][dd] * f1[j];
      a2 += xf[2][dd] * f1[j]; a3 += xf[3][dd] * f1[j];
      b0 += xa[0][dd] * f2[j]; b1 += xa[1][dd] * f2[j];
      b2 += xa[2][dd] * f2[j]; b3 += xa[3][dd] * f2[j];
    }
  }
  Z[(size_t)(r0 + 0) * D + tid] += a0 + b0;
  Z[(size_t)(r0 + 1) * D + tid] += a1 + b1;
  Z[(size_t)(r0 + 2) * D + tid] += a2 + b2;
  Z[(size_t)(r0 + 3) * D + tid] += a3 + b3;
}

// ---- out = LayerNorm(X + Z) * g + b ----
__global__ __launch_bounds__(256) void ln_kernel(const float* __restrict__ X, const float* __restrict__ Z,
    const float* __restrict__ g, const float* __restrict__ bb, float* __restrict__ out) {
  __shared__ float scr[4];
  int row = blockIdx.x, tid = threadIdx.x;
  float h = X[(size_t)row * D + tid] + Z[(size_t)row * D + tid];
  float mu = blockSumF(h, scr) * (1.0f / 256.0f);
  float dv = h - mu;
  float var = blockSumF(dv * dv, scr) * (1.0f / 256.0f);
  float o = dv / sqrtf(var + 1e-5f) * g[tid] + bb[tid];
  out[(size_t)row * D + tid] = o;
}

extern "C" void kernel_launch(void* const* d_in, const int* in_sizes, int n_in,
                              void* d_out, int out_size, void* d_ws, size_t ws_size,
                              hipStream_t stream) {
  const float* X  = (const float*)d_in[0];
  const float* S  = (const float*)d_in[1];
  const float* W1 = (const float*)d_in[2];
  const float* W2 = (const float*)d_in[3];
  const float* W3 = (const float*)d_in[4];
  const float* U1 = (const float*)d_in[5];
  const float* U2 = (const float*)d_in[6];
  const float* g  = (const float*)d_in[7];
  const float* b  = (const float*)d_in[8];

  char* w = (char*)d_ws;
  size_t off = 0;
  auto alloc = [&](size_t bytes) {
    void* p = w + off; off += (bytes + 255) & ~(size_t)255; return p;
  };
  float* A1  = (float*)alloc((size_t)NN * D * 4);
  float* A2  = (float*)alloc((size_t)NN * D * 4);
  float* F1  = (float*)alloc((size_t)NN * D * 4);
  float* F2  = (float*)alloc((size_t)NN * D * 4);
  float* Z   = (float*)alloc((size_t)NN * D * 4);
  float* den = (float*)alloc((size_t)NN * 4);
  float* qf  = (float*)alloc((size_t)NN * DA * 4);
  float* kf  = (float*)alloc((size_t)NN * DA * 4);
  int chunk = 512;
  while (chunk > 64 && off + (size_t)chunk * NN * 4 + 4096 > ws_size) chunk >>= 1;
  float* L32 = (float*)alloc((size_t)chunk * NN * 4);
  (void)in_sizes; (void)n_in; (void)out_size;

  zero_kernel<<<1024, 256, 0, stream>>>(Z, (size_t)NN * D);
  rowsum_kernel<<<NN, 256, 0, stream>>>(S, den);

  const float* XaC = X;  float* XaN = A1;
  const float* XfC = X;  float* XfN = F1;
  for (int n = 0; n < 2; n++) {
    xf_gemm<<<dim3(128, 4), 256, 0, stream>>>(S, XfC, den, XfN);
    qk32_kernel<<<NN, 64, 0, stream>>>(XaC, W1, W2, W3, qf, kf);
    for (int c = 0; c < NN / chunk; c++) {
      logits32<<<dim3(NN / 64, chunk / 64), 256, 0, stream>>>(qf, kf, L32, c * chunk);
      topp_select<<<chunk, 256, 0, stream>>>(L32, XaC, XaN, c * chunk);
    }
    z_accum<<<2048, 256, 0, stream>>>(XfN, XaN, U1 + (size_t)n * D * D, U2 + (size_t)n * D * D, Z);
    XaC = XaN; XaN = A2;
    XfC = XfN; XfN = F2;
  }
  ln_kernel<<<NN, 256, 0, stream>>>(X, Z, g, b, (float*)d_out);
}

// Round 2
// 6081.222 us; speedup vs baseline: 3.5720x; 1.4462x over previous
//
#include <hip/hip_runtime.h>
#include <stdint.h>

#define NN 8192
#define D 256
#define DA 64
#define CAND 2048

typedef unsigned short ushort_t;

// ---- f32 block reductions (256-thread blocks, 4 waves) ----
__device__ float blockSumF(float v, float* scr) {
  __syncthreads();
#pragma unroll
  for (int o = 32; o > 0; o >>= 1) v += __shfl_down(v, o, 64);
  if ((threadIdx.x & 63) == 0) scr[threadIdx.x >> 6] = v;
  __syncthreads();
  return ((scr[0] + scr[1]) + (scr[2] + scr[3]));
}
__device__ float blockMaxF(float v, float* scr) {
  __syncthreads();
#pragma unroll
  for (int o = 32; o > 0; o >>= 1) v = fmaxf(v, __shfl_down(v, o, 64));
  if ((threadIdx.x & 63) == 0) scr[threadIdx.x >> 6] = v;
  __syncthreads();
  return fmaxf(fmaxf(scr[0], scr[1]), fmaxf(scr[2], scr[3]));
}
// ---- inclusive prefix scan across 256 threads (4 waves) ----
__device__ float blockScanIncl(float v, float* wscr) {
#pragma unroll
  for (int off = 1; off < 64; off <<= 1) {
    float u = __shfl_up(v, off, 64);
    if ((threadIdx.x & 63) >= off) v += u;
  }
  __syncthreads();                    // protect wscr reuse
  if ((threadIdx.x & 63) == 63) wscr[threadIdx.x >> 6] = v;
  __syncthreads();
  float add = 0.0f;
  int wid = threadIdx.x >> 6;
  for (int w = 0; w < wid; w++) add += wscr[w];
  return v + add;
}

// ---- zero a float buffer ----
__global__ void zero_kernel(float* __restrict__ p, size_t n) {
  for (size_t i = (size_t)blockIdx.x * blockDim.x + threadIdx.x; i < n;
       i += (size_t)gridDim.x * blockDim.x)
    p[i] = 0.0f;
}

// ---- den[i] = 1 + sum_j S[i][j] ----
__global__ __launch_bounds__(256) void rowsum_kernel(const float* __restrict__ S, float* __restrict__ den) {
  __shared__ float scr[4];
  int row = blockIdx.x, tid = threadIdx.x;
  const float* sr = S + (size_t)row * NN;
  float s = 0;
  for (int c = tid * 4; c < NN; c += 1024) {
    float4 u = *(const float4*)(sr + c);
    s += (u.x + u.y) + (u.z + u.w);
  }
  float tot = blockSumF(s, scr);
  if (tid == 0) den[row] = tot + 1.0f;
}

// ---- Xf_next = (S@Xf + Xf)/den : tiled f32 GEMM, ds_read_b128 inner loop ----
// A-tile stored transposed (Ast[k][r], stride 68 => 16B-aligned rows) so both
// operands are float4 LDS reads: 2x b128 + 16 FMA per k vs old 8x b32.
__global__ __launch_bounds__(256) void xf_gemm(const float* __restrict__ S,
                                               const float* __restrict__ XfC,
                                               const float* __restrict__ den,
                                               float* __restrict__ XfN) {
  __shared__ float Ast[64][68];   // Ast[k][r] = S[rb+r][kt+k]
  __shared__ float Bs[64][68];    // Bs[k][c]  = XfC[kt+k][cb+c]
  int tid = threadIdx.x;
  int tx = tid & 15, ty = tid >> 4;
  int rb = blockIdx.x * 64;
  int cb = blockIdx.y * 64;
  float acc[4][4] = {};
  for (int kt = 0; kt < NN; kt += 64) {
    for (int i = tid; i < 4096; i += 256) {
      int r = i >> 6, c = i & 63;
      Ast[c][r] = S[(size_t)(rb + r) * NN + kt + c];
      Bs[r][c] = XfC[(size_t)(kt + r) * D + cb + c];
    }
    __syncthreads();
#pragma unroll 8
    for (int k = 0; k < 64; k++) {
      float4 av = *(const float4*)&Ast[k][ty * 4];
      float4 bv = *(const float4*)&Bs[k][tx * 4];
      acc[0][0] = fmaf(av.x, bv.x, acc[0][0]); acc[0][1] = fmaf(av.x, bv.y, acc[0][1]);
      acc[0][2] = fmaf(av.x, bv.z, acc[0][2]); acc[0][3] = fmaf(av.x, bv.w, acc[0][3]);
      acc[1][0] = fmaf(av.y, bv.x, acc[1][0]); acc[1][1] = fmaf(av.y, bv.y, acc[1][1]);
      acc[1][2] = fmaf(av.y, bv.z, acc[1][2]); acc[1][3] = fmaf(av.y, bv.w, acc[1][3]);
      acc[2][0] = fmaf(av.z, bv.x, acc[2][0]); acc[2][1] = fmaf(av.z, bv.y, acc[2][1]);
      acc[2][2] = fmaf(av.z, bv.z, acc[2][2]); acc[2][3] = fmaf(av.z, bv.w, acc[2][3]);
      acc[3][0] = fmaf(av.w, bv.x, acc[3][0]); acc[3][1] = fmaf(av.w, bv.y, acc[3][1]);
      acc[3][2] = fmaf(av.w, bv.z, acc[3][2]); acc[3][3] = fmaf(av.w, bv.w, acc[3][3]);
    }
    __syncthreads();
  }
#pragma unroll
  for (int i = 0; i < 4; i++) {
    int r = rb + ty * 4 + i;
    float dinv = 1.0f / den[r];
#pragma unroll
    for (int j = 0; j < 4; j++) {
      int c = cb + tx * 4 + j;
      XfN[(size_t)r * D + c] = (acc[i][j] + XfC[(size_t)r * D + c]) * dinv;
    }
  }
}

// ---- q,k f32: T1 = Xa@W1^T (materialized), q = T1@W2^T, k = Xa@W3^T ----
__global__ __launch_bounds__(64) void qk32_kernel(const float* __restrict__ Xa,
    const float* __restrict__ W1, const float* __restrict__ W2, const float* __restrict__ W3,
    float* __restrict__ qf, float* __restrict__ kf) {
  __shared__ float x[D];
  __shared__ float ts[DA];
  int row = blockIdx.x, tid = threadIdx.x;
  for (int i = tid; i < D; i += 64) x[i] = Xa[(size_t)row * D + i];
  __syncthreads();
  const float* w1r = W1 + (size_t)tid * D;
  const float* w3r = W3 + (size_t)tid * D;
  float t = 0.0f, kv = 0.0f;
  for (int d = 0; d < D; d++) {
    float xv = x[d];
    t  = fmaf(xv, w1r[d], t);
    kv = fmaf(xv, w3r[d], kv);
  }
  kf[(size_t)row * DA + tid] = kv;
  ts[tid] = t;
  __syncthreads();
  const float* w2r = W2 + (size_t)tid * DA;
  float qv = 0.0f;
  for (int a = 0; a < DA; a++) qv = fmaf(ts[a], w2r[a], qv);
  qf[(size_t)row * DA + tid] = qv;
}

// ---- L[chunk] = q @ k^T  f32 ----
__global__ __launch_bounds__(256) void logits32(const float* __restrict__ qf,
    const float* __restrict__ kf, float* __restrict__ L, int rowBase) {
  __shared__ float qs[64][65];
  __shared__ float ks[64][65];
  int tid = threadIdx.x;
  int tx = tid & 15, ty = tid >> 4;
  int colTile = blockIdx.x * 64;
  int rowTile = blockIdx.y * 64;
  for (int i = tid; i < 4096; i += 256) {
    int r = i >> 6, c = i & 63;
    qs[c][r] = qf[(size_t)(rowBase + rowTile + r) * DA + c];
    ks[c][r] = kf[(size_t)(colTile + r) * DA + c];
  }
  __syncthreads();
  float acc[4][4] = {};
  for (int c = 0; c < 64; c++) {
    float a0 = qs[c][ty * 4], a1 = qs[c][ty * 4 + 1];
    float a2 = qs[c][ty * 4 + 2], a3 = qs[c][ty * 4 + 3];
    float b0 = ks[c][tx * 4], b1 = ks[c][tx * 4 + 1];
    float b2 = ks[c][tx * 4 + 2], b3 = ks[c][tx * 4 + 3];
    acc[0][0] = fmaf(a0, b0, acc[0][0]); acc[0][1] = fmaf(a0, b1, acc[0][1]);
    acc[0][2] = fmaf(a0, b2, acc[0][2]); acc[0][3] = fmaf(a0, b3, acc[0][3]);
    acc[1][0] = fmaf(a1, b0, acc[1][0]); acc[1][1] = fmaf(a1, b1, acc[1][1]);
    acc[1][2] = fmaf(a1, b2, acc[1][2]); acc[1][3] = fmaf(a1, b3, acc[1][3]);
    acc[2][0] = fmaf(a2, b0, acc[2][0]); acc[2][1] = fmaf(a2, b1, acc[2][1]);
    acc[2][2] = fmaf(a2, b2, acc[2][2]); acc[2][3] = fmaf(a2, b3, acc[2][3]);
    acc[3][0] = fmaf(a3, b0, acc[3][0]); acc[3][1] = fmaf(a3, b1, acc[3][1]);
    acc[3][2] = fmaf(a3, b2, acc[3][2]); acc[3][3] = fmaf(a3, b3, acc[3][3]);
  }
#pragma unroll
  for (int i = 0; i < 4; i++)
#pragma unroll
    for (int j = 0; j < 4; j++)
      L[(size_t)(rowTile + ty * 4 + i) * NN + colTile + tx * 4 + j] = acc[i][j];
}

// ---- FULL-ROW top-p via histogram refinement. NO SORT, NO TRUNCATION. ----
// softmax (np pairwise Z, identical) -> 256-bucket histogram on float-key
// (exp + 3 mantissa bits) -> descending mass scan finds crossing bucket ->
// refine boundary bucket by 8/8/4 more bits (exact f32 value) ->
// exact stop value t* + idx tie-break => kept iff u>t* || (u==t* && j<=icut).
// Works for peaked AND flat rows; deterministic up to f32 atomic-order ~1e-7.
__global__ __launch_bounds__(256) void topp_histsel(const float* __restrict__ L,
    const float* __restrict__ XaOld, float* __restrict__ XaNew, int rowBase) {
  __shared__ float ps[NN];          // 32 KB probs (in place over logits)
  __shared__ float hsum[256];       // per-bucket mass
  __shared__ float hcntf[256];      // per-bucket count (exact in f32)
  __shared__ float cv[CAND];        // compacted kept probs
  __shared__ ushort_t ci[CAND];     // compacted kept indices
  __shared__ float wsum[4][256];    // per-wave partial output
  __shared__ float wscr[4];
  __shared__ float scr[4];
  __shared__ float zsh;
  __shared__ unsigned sh_lo, sh_hi, sh_tie;
  __shared__ float sh_M, sh_asum, sh_hs;
  __shared__ int sh_C, sh_cross, sh_hc, sh_icut, sh_nkt, sh_ntot, sh_cnt;

  int tid = threadIdx.x;
  const float* Lr = L + (size_t)blockIdx.x * NN;
  // 1. load logits (vectorized), row max
  float lm = -INFINITY;
  for (int c = tid * 4; c < NN; c += 1024) {
    float4 u = *(const float4*)(Lr + c);
    ps[c] = u.x; ps[c + 1] = u.y; ps[c + 2] = u.z; ps[c + 3] = u.w;
    lm = fmaxf(fmaxf(lm, fmaxf(u.x, u.y)), fmaxf(u.z, u.w));
  }
  float m = blockMaxF(lm, scr);   // entry barrier publishes ps
  // 2. Z = numpy pairwise_sum of exp(l - m): 64 leaves x 128 elems (8-acc base)
  if (tid < 64) {
    int base = tid * 128;
    float r[8];
#pragma unroll
    for (int j = 0; j < 8; j++) r[j] = expf(ps[base + j] - m);
    for (int i = 8; i < 128; i += 8)
#pragma unroll
      for (int j = 0; j < 8; j++) r[j] += expf(ps[base + i + j] - m);
    float leaf = ((r[0] + r[1]) + (r[2] + r[3])) + ((r[4] + r[5]) + (r[6] + r[7]));
#pragma unroll
    for (int off = 1; off < 64; off <<= 1) leaf += __shfl_down(leaf, off, 64);
    if (tid == 0) zsh = leaf;
  }
  hsum[tid] = 0.0f; hcntf[tid] = 0.0f;
  if (tid == 0) { sh_M = 0.0f; sh_C = 0; sh_cross = 256; }
  __syncthreads();
  float z = zsh;
  // 3. probs in place + level-0 histogram: bucket = (bits>>20)-768,
  // monotone in p; b<0 => p < 2^-31, skipped (tail mass < 4e-6).
  for (int j = tid; j < NN; j += 256) {
    float p = expf(ps[j] - m) / z;
    ps[j] = p;
    int b = (int)(__float_as_uint(p) >> 20) - 768;
    if (b >= 0) { atomicAdd(&hsum[b], p); atomicAdd(&hcntf[b], 1.0f); }
  }
  __syncthreads();
  // 4. level scans: crossing bucket = largest value-bucket where
  // (mass above) + (bucket mass) >= 0.9. Refine until bucket holds 1 item
  // or the bucket is a single float value (level 3).
  for (int lev = 0; lev < 4; lev++) {
    float x  = hsum[255 - tid];
    float xc = hcntf[255 - tid];
    float inclm = blockScanIncl(x, wscr);
    float inclc = blockScanIncl(xc, wscr);
    if (sh_M + inclm >= 0.9f) atomicMin(&sh_cross, tid);
    __syncthreads();
    int ct = sh_cross; if (ct == 256) ct = 255;   // guard (cannot miss)
    if (tid == ct) {
      int key = 255 - tid;
      sh_M = sh_M + (inclm - x);
      sh_C = sh_C + (int)(inclc - xc + 0.5f);
      sh_hs = x; sh_hc = (int)(xc + 0.5f);
      unsigned nlo, nhi;
      if (lev == 0) { nlo = (unsigned)(768 + key) << 20; nhi = nlo + (1u << 20); }
      else {
        int s = (lev == 1) ? 12 : (lev == 2) ? 4 : 0;
        nlo = sh_lo + ((unsigned)key << s); nhi = nlo + (1u << s);
      }
      sh_lo = nlo; sh_hi = nhi;
    }
    __syncthreads();
    if (sh_hc == 1 || lev == 3) break;   // uniform
    // rebuild histogram within [sh_lo, sh_hi)
    hsum[tid] = 0.0f; hcntf[tid] = 0.0f;
    if (tid == 0) sh_cross = 256;
    __syncthreads();
    unsigned rlo = sh_lo, rhi = sh_hi;
    int s2 = (lev == 0) ? 12 : (lev == 1) ? 4 : 0;
    unsigned msk = (lev == 2) ? 15u : 255u;
    for (int j = tid; j < NN; j += 256) {
      unsigned u = __float_as_uint(ps[j]);
      if (u >= rlo && u < rhi) {
        unsigned key = (u >> s2) & msk;
        atomicAdd(&hsum[key], ps[j]); atomicAdd(&hcntf[key], 1.0f);
      }
    }
    __syncthreads();
  }
  // 5. finalize: stop value + tie count (reference: keep while prefix < 0.9)
  if (tid == 0) {
    if (sh_hc == 1) {
      // unique boundary item; its prefix = sh_M < 0.9 always => kept
      sh_tie = sh_lo; sh_nkt = 1; sh_asum = sh_M + sh_hs; sh_icut = NN;
    } else {
      // exact single value (range width 1): sequential f32 tie walk
      float tiev = __uint_as_float(sh_lo);
      float cs = sh_M; int n = 0; int nt = sh_hc;
      while (n < nt && cs < 0.9f) { cs += tiev; n++; }
      sh_tie = sh_lo; sh_nkt = n; sh_asum = cs;
      sh_icut = (n == nt) ? NN : ((n == 0) ? -1 : -2);   // -2 => bisect idx
    }
    sh_ntot = sh_C + sh_nkt;
    sh_cnt = 0;
  }
  __syncthreads();
  // 5b. degenerate ties (many items at exactly t*): idx-ascending cutoff
  if (sh_icut == -2) {
    int need = sh_nkt; unsigned tb = sh_tie;
    int lo_ = 0, hi_ = NN - 1;
    for (int it = 0; it < 13; it++) {
      int mid = (lo_ + hi_) >> 1;
      float c = 0.0f;
      for (int j = tid; j < NN; j += 256)
        if (__float_as_uint(ps[j]) == tb && j <= mid) c += 1.0f;
      c = blockSumF(c, scr);
      if (c >= (float)need) hi_ = mid; else lo_ = mid + 1;
    }
    if (tid == 0) sh_icut = hi_;
    __syncthreads();
  }
  // 6. gather: wave w accumulates every 4th kept item; 64 lanes x float4 = row
  unsigned tie = sh_tie; int icut = sh_icut;
  float asum = fmaxf(sh_asum, 1e-12f);
  int ntot = sh_ntot;
  int wid = tid >> 6, lane = tid & 63;
  float4 acc; acc.x = acc.y = acc.z = acc.w = 0.0f;
  if (ntot <= CAND) {
    for (int j = tid; j < NN; j += 256) {
      float p = ps[j]; unsigned u = __float_as_uint(p);
      if (u > tie || (u == tie && j <= icut)) {
        int s = atomicAdd(&sh_cnt, 1);
        cv[s] = p; ci[s] = (ushort_t)j;
      }
    }
    __syncthreads();
    int nc = sh_cnt;
    for (int i = wid; i < nc; i += 4) {
      float pw = cv[i] / asum;
      const float4 xv = *(const float4*)(XaOld + (size_t)ci[i] * D + lane * 4);
      acc.x = fmaf(pw, xv.x, acc.x); acc.y = fmaf(pw, xv.y, acc.y);
      acc.z = fmaf(pw, xv.z, acc.z); acc.w = fmaf(pw, xv.w, acc.w);
    }
  } else {
    // large nucleus: predicate scan, no compaction needed
    for (int j = wid; j < NN; j += 4) {
      float p = ps[j]; unsigned u = __float_as_uint(p);
      if (u > tie || (u == tie && j <= icut)) {
        float pw = p / asum;
        const float4 xv = *(const float4*)(XaOld + (size_t)j * D + lane * 4);
        acc.x = fmaf(pw, xv.x, acc.x); acc.y = fmaf(pw, xv.y, acc.y);
        acc.z = fmaf(pw, xv.z, acc.z); acc.w = fmaf(pw, xv.w, acc.w);
      }
    }
    __syncthreads();
  }
  *(float4*)&wsum[wid][lane * 4] = acc;
  __syncthreads();
  int col = tid;
  float o = (wsum[0][col] + wsum[1][col]) + (wsum[2][col] + wsum[3][col]);
  XaNew[(size_t)(rowBase + blockIdx.x) * D + col] = o;
}

// ---- Z += Xf@U1^T + Xa@U2^T  (4 rows per block) ----
__global__ __launch_bounds__(256) void z_accum(const float* __restrict__ Xf, const float* __restrict__ Xa,
    const float* __restrict__ U1n, const float* __restrict__ U2n, float* __restrict__ Z) {
  __shared__ float xf[4][D];
  __shared__ float xa[4][D];
  int r0 = blockIdx.x * 4, tid = threadIdx.x;
  for (int i = tid; i < 4 * D; i += 256) {
    xf[i >> 8][i & 255] = Xf[(size_t)r0 * D + i];
    xa[i >> 8][i & 255] = Xa[(size_t)r0 * D + i];
  }
  __syncthreads();
  const float* u1r = U1n + (size_t)tid * D;
  const float* u2r = U2n + (size_t)tid * D;
  float a0 = 0, a1 = 0, a2 = 0, a3 = 0, b0 = 0, b1 = 0, b2 = 0, b3 = 0;
  for (int d = 0; d < D; d += 4) {
    float4 u1 = *(const float4*)(u1r + d);
    float4 u2 = *(const float4*)(u2r + d);
    float f1[4] = {u1.x, u1.y, u1.z, u1.w};
    float f2[4] = {u2.x, u2.y, u2.z, u2.w};
#pragma unroll
    for (int j = 0; j < 4; j++) {
      int dd = d + j;
      a0 += xf[0][dd] * f1[j]; a1 += xf[1][dd] * f1[j];
      a2 += xf[2][dd] * f1[j]; a3 += xf[3][dd] * f1[j];
      b0 += xa[0][dd] * f2[j]; b1 += xa[1][dd] * f2[j];
      b2 += xa[2][dd] * f2[j]; b3 += xa[3][dd] * f2[j];
    }
  }
  Z[(size_t)(r0 + 0) * D + tid] += a0 + b0;
  Z[(size_t)(r0 + 1) * D + tid] += a1 + b1;
  Z[(size_t)(r0 + 2) * D + tid] += a2 + b2;
  Z[(size_t)(r0 + 3) * D + tid] += a3 + b3;
}

// ---- out = LayerNorm(X + Z) * g + b ----
__global__ __launch_bounds__(256) void ln_kernel(const float* __restrict__ X, const float* __restrict__ Z,
    const float* __restrict__ g, const float* __restrict__ bb, float* __restrict__ out) {
  __shared__ float scr[4];
  int row = blockIdx.x, tid = threadIdx.x;
  float h = X[(size_t)row * D + tid] + Z[(size_t)row * D + tid];
  float mu = blockSumF(h, scr) * (1.0f / 256.0f);
  float dv = h - mu;
  float var = blockSumF(dv * dv, scr) * (1.0f / 256.0f);
  float o = dv / sqrtf(var + 1e-5f) * g[tid] + bb[tid];
  out[(size_t)row * D + tid] = o;
}

extern "C" void kernel_launch(void* const* d_in, const int* in_sizes, int n_in,
                              void* d_out, int out_size, void* d_ws, size_t ws_size,
                              hipStream_t stream) {
  const float* X  = (const float*)d_in[0];
  const float* S  = (const float*)d_in[1];
  const float* W1 = (const float*)d_in[2];
  const float* W2 = (const float*)d_in[3];
  const float* W3 = (const float*)d_in[4];
  const float* U1 = (const float*)d_in[5];
  const float* U2 = (const float*)d_in[6];
  const float* g  = (const float*)d_in[7];
  const float* b  = (const float*)d_in[8];

  char* w = (char*)d_ws;
  size_t off = 0;
  auto alloc = [&](size_t bytes) {
    void* p = w + off; off += (bytes + 255) & ~(size_t)255; return p;
  };
  float* A1  = (float*)alloc((size_t)NN * D * 4);
  float* A2  = (float*)alloc((size_t)NN * D * 4);
  float* F1  = (float*)alloc((size_t)NN * D * 4);
  float* F2  = (float*)alloc((size_t)NN * D * 4);
  float* Z   = (float*)alloc((size_t)NN * D * 4);
  float* den = (float*)alloc((size_t)NN * 4);
  float* qf  = (float*)alloc((size_t)NN * DA * 4);
  float* kf  = (float*)alloc((size_t)NN * DA * 4);
  int chunk = 512;
  while (chunk > 64 && off + (size_t)chunk * NN * 4 + 4096 > ws_size) chunk >>= 1;
  float* L32 = (float*)alloc((size_t)chunk * NN * 4);
  (void)in_sizes; (void)n_in; (void)out_size;

  zero_kernel<<<1024, 256, 0, stream>>>(Z, (size_t)NN * D);
  rowsum_kernel<<<NN, 256, 0, stream>>>(S, den);

  const float* XaC = X;  float* XaN = A1;
  const float* XfC = X;  float* XfN = F1;
  for (int n = 0; n < 2; n++) {
    xf_gemm<<<dim3(128, 4), 256, 0, stream>>>(S, XfC, den, XfN);
    qk32_kernel<<<NN, 64, 0, stream>>>(XaC, W1, W2, W3, qf, kf);
    for (int c = 0; c < NN / chunk; c++) {
      logits32<<<dim3(NN / 64, chunk / 64), 256, 0, stream>>>(qf, kf, L32, c * chunk);
      topp_histsel<<<chunk, 256, 0, stream>>>(L32, XaC, XaN, c * chunk);
    }
    z_accum<<<2048, 256, 0, stream>>>(XfN, XaN, U1 + (size_t)n * D * D, U2 + (size_t)n * D * D, Z);
    XaC = XaN; XaN = A2;
    XfC = XfN; XfN = F2;
  }
  ln_kernel<<<NN, 256, 0, stream>>>(X, Z, g, b, (float*)d_out);
}